// Round 12
// baseline (37.094 us; speedup 1.0000x reference)
//
#include <hip/hip_runtime.h>
#include <math.h>

#define NH 4    // heads
#define DH 8    // head dim
#define NF 64   // F
#define NT 12   // T
#define NB 2    // batch
#define IT 4    // i-rows tiled per score block

// Branchless exact-gelu: x * 0.5 * (1 + erf(x/sqrt(2))).
// erf via Abramowitz-Stegun 7.1.26 (max abs err 1.5e-7), no divergence.
__device__ __forceinline__ float gelu_f(float x) {
    const float s = x * 0.70710678118654752440f;
    const float z = __builtin_fabsf(s);
    const float t = __builtin_amdgcn_rcpf(fmaf(0.3275911f, z, 1.0f));
    float p = fmaf(1.061405429f, t, -1.453152027f);
    p = fmaf(p, t, 1.421413741f);
    p = fmaf(p, t, -0.284496736f);
    p = fmaf(p, t, 0.254829592f);
    p *= t;
    const float e = __builtin_amdgcn_exp2f(z * z * -1.44269504088896340736f); // exp(-z^2)
    const float erfa = fmaf(-p, e, 1.0f);                      // erf(|s|)
    const float erfv = __builtin_copysignf(erfa, s);           // erf(s)
    return 0.5f * x * (1.0f + erfv);
}

// One wave (64 lanes) per (b,n) row; lane = f. (R4 version, unchanged.)
__global__ __launch_bounds__(256) void qk_kernel(
    const float* __restrict__ x, const float* __restrict__ w1,
    const float* __restrict__ W2, const float* __restrict__ a,
    float* __restrict__ sqT, float* __restrict__ skT, int N)
{
    __shared__ float Wq[NF][NH + 1];
    __shared__ float Wk[NF][NH + 1];
    const int t = threadIdx.x;

    {
        int f = t >> 2, h = t & 3;
        float accq = 0.f, acck = 0.f;
        #pragma unroll
        for (int k = 0; k < DH; ++k) {
            float w = W2[f * (NH * DH) + h * DH + k];
            accq += w * a[k];
            acck += w * a[DH + k];
        }
        Wq[f][h] = accq;
        Wk[f][h] = acck;
    }
    __syncthreads();

    float w1r[NT];
    #pragma unroll
    for (int i = 0; i < NT; ++i) w1r[i] = w1[i];

    const int wave = t >> 6;
    const int lane = t & 63;                      // = f
    const long long row = (long long)blockIdx.x * 4 + wave;   // in [0, NB*N)
    if (row >= (long long)NB * N) return;

    const float* xr = x + row * (NF * NT) + (long long)lane * NT;
    float4 v0 = *(const float4*)(xr);
    float4 v1 = *(const float4*)(xr + 4);
    float4 v2 = *(const float4*)(xr + 8);
    float dot = v0.x*w1r[0] + v0.y*w1r[1] + v0.z*w1r[2]  + v0.w*w1r[3]
              + v1.x*w1r[4] + v1.y*w1r[5] + v1.z*w1r[6]  + v1.w*w1r[7]
              + v2.x*w1r[8] + v2.y*w1r[9] + v2.z*w1r[10] + v2.w*w1r[11];
    float q = gelu_f(dot);

    float acc[8];
    #pragma unroll
    for (int h = 0; h < NH; ++h) {
        acc[h]     = q * Wq[lane][h];
        acc[4 + h] = q * Wk[lane][h];
    }
    #pragma unroll
    for (int ofs = 32; ofs > 0; ofs >>= 1) {
        #pragma unroll
        for (int i = 0; i < 8; ++i)
            acc[i] += __shfl_xor(acc[i], ofs, 64);
    }
    if (lane < 8) {
        int h   = lane & 3;
        int isK = lane >> 2;
        int b   = (int)(row / N);
        int n   = (int)(row % N);
        float* dst = isK ? skT : sqT;
        dst[((long long)b * NH + h) * N + n] = acc[lane];
    }
}

// R12: stream-axis maximum. 512 threads = 8 waves; window = FULL row (N cols),
// IT=4 rows. Wave w exclusively owns bh=w: it writes rows i0..i0+3 of plane
// bh — one contiguous 32KB ascending region per wave (zero stream
// interleaving within a wave). adj staged once in 32KB LDS (pre-scaled by
// aadj, read once from HBM exactly like the champion); skT register-held
// (8 float4/thread); sq are wave-uniform scalar loads. Requires N%(512*4)==0.
__global__ __launch_bounds__(512) void score_kernel_wavebh(
    const float* __restrict__ adj, const float* __restrict__ sqT,
    const float* __restrict__ skT, const float* __restrict__ a,
    float* __restrict__ out, int N)
{
    const float aadj = a[2 * DH];
    const int t  = threadIdx.x;                     // 0..511
    const int i0 = (int)blockIdx.x * IT;

    extern __shared__ float adjS[];                 // [IT][N] floats, pre-scaled

    #pragma unroll
    for (int r = 0; r < IT; ++r) {
        float4 v = *(const float4*)(adj + (long long)(i0 + r) * N + (t << 2));
        float4 sv; sv.x = v.x * aadj; sv.y = v.y * aadj;
                   sv.z = v.z * aadj; sv.w = v.w * aadj;
        *(float4*)&adjS[r * N + (t << 2)] = sv;
    }
    __syncthreads();

    const int wave = t >> 6;                        // = bh (0..7)
    const int lane = t & 63;
    const int nq   = N >> 2;                        // quads per row
    const int KQ   = nq >> 6;                       // quads per lane (8 at N=2048)

    // Register-stage this wave's skT for the full row: KQ float4 per thread.
    float4 sk[8];
    #pragma unroll
    for (int k = 0; k < 8; ++k) {
        if (k < KQ)
            sk[k] = *(const float4*)(skT + (long long)wave * N + ((lane + (k << 6)) << 2));
    }

    #pragma unroll
    for (int ii = 0; ii < IT; ++ii) {
        const float sq = sqT[(long long)wave * N + i0 + ii];   // wave-uniform
        float* orow = out + ((long long)wave * N + i0 + ii) * N;
        #pragma unroll
        for (int k = 0; k < 8; ++k) {
            if (k < KQ) {
                const int qw = lane + (k << 6);     // quad within row
                const float* ar = &adjS[ii * N + (qw << 2)];
                float4 o;
                o.x = gelu_f(sq + sk[k].x + ar[0]);
                o.y = gelu_f(sq + sk[k].y + ar[1]);
                o.z = gelu_f(sq + sk[k].z + ar[2]);
                o.w = gelu_f(sq + sk[k].w + ar[3]);
                *(float4*)(orow + (qw << 2)) = o;
            }
        }
    }
}

// Fallback (exact R4 kernel) for shapes where the mapping doesn't divide.
__global__ __launch_bounds__(256) void score_kernel_flat(
    const float* __restrict__ adj, const float* __restrict__ sqT,
    const float* __restrict__ skT, const float* __restrict__ a,
    float* __restrict__ out, int N)
{
    const float aadj = a[2 * DH];
    const int nq = N >> 2;
    long long tid = (long long)blockIdx.x * blockDim.x + threadIdx.x;
    if (tid >= (long long)N * nq) return;
    const int i  = (int)(tid / nq);
    const int j0 = (int)(tid % nq) << 2;

    float4 adj4 = *(const float4*)(adj + (long long)i * N + j0);
    const float a0 = adj4.x * aadj;
    const float a1 = adj4.y * aadj;
    const float a2 = adj4.z * aadj;
    const float a3 = adj4.w * aadj;

    #pragma unroll
    for (int bh = 0; bh < NB * NH; ++bh) {
        const float sq = sqT[(long long)bh * N + i];
        float4 sk4 = *(const float4*)(skT + (long long)bh * N + j0);
        float4 o;
        o.x = gelu_f(sq + sk4.x + a0);
        o.y = gelu_f(sq + sk4.y + a1);
        o.z = gelu_f(sq + sk4.z + a2);
        o.w = gelu_f(sq + sk4.w + a3);
        *(float4*)(out + ((long long)bh * N + i) * N + j0) = o;
    }
}

extern "C" void kernel_launch(void* const* d_in, const int* in_sizes, int n_in,
                              void* d_out, int out_size, void* d_ws, size_t ws_size,
                              hipStream_t stream)
{
    const float* x   = (const float*)d_in[0];
    const float* adj = (const float*)d_in[1];
    const float* w1  = (const float*)d_in[2];
    const float* W2  = (const float*)d_in[3];
    const float* a   = (const float*)d_in[4];
    float* out = (float*)d_out;

    // N from adj (N*N elements); B fixed at 2 per reference setup.
    int N = 1;
    while ((long long)(N + 1) * (N + 1) <= (long long)in_sizes[1]) ++N;

    float* sqT = (float*)d_ws;                 // NB*NH*N floats
    float* skT = sqT + (size_t)NB * NH * N;    // NB*NH*N floats

    const int rows = NB * N;                   // one wave per row, 4 waves/block
    qk_kernel<<<(rows + 3) / 4, 256, 0, stream>>>(x, w1, W2, a, sqT, skT, N);

    // wave-per-bh kernel needs: N divisible by 2048 (512 threads x 4-quad),
    // nq/64 <= 8 ... exactly N==2048 geometry, else flat fallback.
    if (N == 2048) {
        const size_t ldsBytes = (size_t)IT * N * sizeof(float);   // 32 KB
        score_kernel_wavebh<<<N / IT, 512, ldsBytes, stream>>>(adj, sqT, skT, a, out, N);
    } else {
        const int nq = N >> 2;
        const long long total = (long long)N * nq;
        score_kernel_flat<<<(int)((total + 255) / 256), 256, 0, stream>>>(adj, sqT, skT, a, out, N);
    }
}

// Round 13
// 34.377 us; speedup vs baseline: 1.0790x; 1.0790x over previous
//
#include <hip/hip_runtime.h>
#include <math.h>

#define NH 4    // heads
#define DH 8    // head dim
#define NF 64   // F
#define NT 12   // T
#define NB 2    // batch
#define IT 4    // i-rows tiled per score block

// Branchless exact-gelu: x * 0.5 * (1 + erf(x/sqrt(2))).
// erf via Abramowitz-Stegun 7.1.26 (max abs err 1.5e-7), no divergence.
__device__ __forceinline__ float gelu_f(float x) {
    const float s = x * 0.70710678118654752440f;
    const float z = __builtin_fabsf(s);
    const float t = __builtin_amdgcn_rcpf(fmaf(0.3275911f, z, 1.0f));
    float p = fmaf(1.061405429f, t, -1.453152027f);
    p = fmaf(p, t, 1.421413741f);
    p = fmaf(p, t, -0.284496736f);
    p = fmaf(p, t, 0.254829592f);
    p *= t;
    const float e = __builtin_amdgcn_exp2f(z * z * -1.44269504088896340736f); // exp(-z^2)
    const float erfa = fmaf(-p, e, 1.0f);                      // erf(|s|)
    const float erfv = __builtin_copysignf(erfa, s);           // erf(s)
    return 0.5f * x * (1.0f + erfv);
}

// One wave (64 lanes) per (b,n) row; lane = f.
__global__ __launch_bounds__(256) void qk_kernel(
    const float* __restrict__ x, const float* __restrict__ w1,
    const float* __restrict__ W2, const float* __restrict__ a,
    float* __restrict__ sqT, float* __restrict__ skT, int N)
{
    __shared__ float Wq[NF][NH + 1];
    __shared__ float Wk[NF][NH + 1];
    const int t = threadIdx.x;

    {
        int f = t >> 2, h = t & 3;
        float accq = 0.f, acck = 0.f;
        #pragma unroll
        for (int k = 0; k < DH; ++k) {
            float w = W2[f * (NH * DH) + h * DH + k];
            accq += w * a[k];
            acck += w * a[DH + k];
        }
        Wq[f][h] = accq;
        Wk[f][h] = acck;
    }
    __syncthreads();

    float w1r[NT];
    #pragma unroll
    for (int i = 0; i < NT; ++i) w1r[i] = w1[i];

    const int wave = t >> 6;
    const int lane = t & 63;                      // = f
    const long long row = (long long)blockIdx.x * 4 + wave;   // in [0, NB*N)
    if (row >= (long long)NB * N) return;

    const float* xr = x + row * (NF * NT) + (long long)lane * NT;
    float4 v0 = *(const float4*)(xr);
    float4 v1 = *(const float4*)(xr + 4);
    float4 v2 = *(const float4*)(xr + 8);
    float dot = v0.x*w1r[0] + v0.y*w1r[1] + v0.z*w1r[2]  + v0.w*w1r[3]
              + v1.x*w1r[4] + v1.y*w1r[5] + v1.z*w1r[6]  + v1.w*w1r[7]
              + v2.x*w1r[8] + v2.y*w1r[9] + v2.z*w1r[10] + v2.w*w1r[11];
    float q = gelu_f(dot);

    float acc[8];
    #pragma unroll
    for (int h = 0; h < NH; ++h) {
        acc[h]     = q * Wq[lane][h];
        acc[4 + h] = q * Wk[lane][h];
    }
    #pragma unroll
    for (int ofs = 32; ofs > 0; ofs >>= 1) {
        #pragma unroll
        for (int i = 0; i < 8; ++i)
            acc[i] += __shfl_xor(acc[i], ofs, 64);
    }
    if (lane < 8) {
        int h   = lane & 3;
        int isK = lane >> 2;
        int b   = (int)(row / N);
        int n   = (int)(row % N);
        float* dst = isK ? skT : sqT;
        dst[((long long)b * NH + h) * N + n] = acc[lane];
    }
}

// Champion (R11): block = 4 waves, window = 256 quads (1024 cols) x IT=4 rows.
// adj window pre-scaled by aadj staged ONCE in 16KB LDS. Each wave handles
// 2 bh values (per-wave far-apart write streams 8 -> 2, 4KB contiguous runs).
// skT register-held per (wave,bh).
__global__ __launch_bounds__(256) void score_kernel_lds(
    const float* __restrict__ adj, const float* __restrict__ sqT,
    const float* __restrict__ skT, const float* __restrict__ a,
    float* __restrict__ out, int N)
{
    const float aadj = a[2 * DH];
    const int t   = threadIdx.x;
    const int nq  = N >> 2;
    const int wpr = nq >> 8;                        // 256-quad windows per row
    const int ig  = blockIdx.x / wpr;
    const int w   = blockIdx.x - ig * wpr;
    const int i0  = ig * IT;
    const int q0  = w << 8;                         // first quad of window

    __shared__ float adjS[IT][1024];                // 16KB, pre-scaled by aadj

    #pragma unroll
    for (int r = 0; r < IT; ++r) {
        float4 v = *(const float4*)(adj + (long long)(i0 + r) * N + ((q0 + t) << 2));
        float4 sv; sv.x = v.x * aadj; sv.y = v.y * aadj;
                   sv.z = v.z * aadj; sv.w = v.w * aadj;
        *(float4*)&adjS[r][t << 2] = sv;
    }
    __syncthreads();

    const int wave = t >> 6;
    const int lane = t & 63;

    #pragma unroll
    for (int bb = 0; bb < 2; ++bb) {
        const int bh = (wave << 1) + bb;

        float4 sk[4];
        #pragma unroll
        for (int k = 0; k < 4; ++k)
            sk[k] = *(const float4*)(skT + (long long)bh * N + ((q0 + lane + (k << 6)) << 2));

        #pragma unroll
        for (int ii = 0; ii < IT; ++ii) {
            const float sq = sqT[(long long)bh * N + i0 + ii];
            #pragma unroll
            for (int k = 0; k < 4; ++k) {
                const int qw = lane + (k << 6);     // quad within window
                const float* ar = &adjS[ii][qw << 2];
                float4 o;
                o.x = gelu_f(sq + sk[k].x + ar[0]);
                o.y = gelu_f(sq + sk[k].y + ar[1]);
                o.z = gelu_f(sq + sk[k].z + ar[2]);
                o.w = gelu_f(sq + sk[k].w + ar[3]);
                *(float4*)(out + ((long long)bh * N + i0 + ii) * N + ((q0 + qw) << 2)) = o;
            }
        }
    }
}

// Fallback (exact R4 kernel) for shapes where the tiled mapping doesn't divide.
__global__ __launch_bounds__(256) void score_kernel_flat(
    const float* __restrict__ adj, const float* __restrict__ sqT,
    const float* __restrict__ skT, const float* __restrict__ a,
    float* __restrict__ out, int N)
{
    const float aadj = a[2 * DH];
    const int nq = N >> 2;
    long long tid = (long long)blockIdx.x * blockDim.x + threadIdx.x;
    if (tid >= (long long)N * nq) return;
    const int i  = (int)(tid / nq);
    const int j0 = (int)(tid % nq) << 2;

    float4 adj4 = *(const float4*)(adj + (long long)i * N + j0);
    const float a0 = adj4.x * aadj;
    const float a1 = adj4.y * aadj;
    const float a2 = adj4.z * aadj;
    const float a3 = adj4.w * aadj;

    #pragma unroll
    for (int bh = 0; bh < NB * NH; ++bh) {
        const float sq = sqT[(long long)bh * N + i];
        float4 sk4 = *(const float4*)(skT + (long long)bh * N + j0);
        float4 o;
        o.x = gelu_f(sq + sk4.x + a0);
        o.y = gelu_f(sq + sk4.y + a1);
        o.z = gelu_f(sq + sk4.z + a2);
        o.w = gelu_f(sq + sk4.w + a3);
        *(float4*)(out + ((long long)bh * N + i) * N + j0) = o;
    }
}

extern "C" void kernel_launch(void* const* d_in, const int* in_sizes, int n_in,
                              void* d_out, int out_size, void* d_ws, size_t ws_size,
                              hipStream_t stream)
{
    const float* x   = (const float*)d_in[0];
    const float* adj = (const float*)d_in[1];
    const float* w1  = (const float*)d_in[2];
    const float* W2  = (const float*)d_in[3];
    const float* a   = (const float*)d_in[4];
    float* out = (float*)d_out;

    // N from adj (N*N elements); B fixed at 2 per reference setup.
    int N = 1;
    while ((long long)(N + 1) * (N + 1) <= (long long)in_sizes[1]) ++N;

    float* sqT = (float*)d_ws;                 // NB*NH*N floats
    float* skT = sqT + (size_t)NB * NH * N;    // NB*NH*N floats

    const int rows = NB * N;                   // one wave per row, 4 waves/block
    qk_kernel<<<(rows + 3) / 4, 256, 0, stream>>>(x, w1, W2, a, sqT, skT, N);

    const int nq = N >> 2;
    if ((nq & 255) == 0 && (N % IT) == 0) {
        const int wpr = nq >> 8;
        const int blocks = (N / IT) * wpr;     // 1024 at N=2048
        score_kernel_lds<<<blocks, 256, 0, stream>>>(adj, sqT, skT, a, out, N);
    } else {
        const long long total = (long long)N * nq;
        score_kernel_flat<<<(int)((total + 255) / 256), 256, 0, stream>>>(adj, sqT, skT, a, out, N);
    }
}